// Round 7
// baseline (63.496 us; speedup 1.0000x reference)
//
#include <hip/hip_runtime.h>
#include <hip/hip_fp16.h>

// GeneSymbolCNN: embed(67x32, pad0) -> conv1d k=2/3/4 (32ch) + ReLU + max_t
//                -> concat(96) -> 96x96 linear + ReLU.
// Conv-over-embedding factors into per-token f16 tables:
//   T_{k,h}[v][c] = sum_e embed[v,e] * w_k[c,e,h]  (bias folded into h=0)
// R7 vs R6 (fused ~40us, single-pipe LDS-bound ~26us floor):
//  * PIPE SPLIT: conv2+conv3 (72 reads/thread) from LDS (parity-replicated
//    128B lines, 5 tables = 42.9KB); conv4 (52 reads/thread) from GLOBAL --
//    its 4 tables are 17.1KB of 64B-line entries, L1-resident. Two pipes
//    run concurrently: LDS ~12-15us || L1 ~11us || VALU ~7us.
//  * Shared address array ag[16] (global form tok*64+c*16); LDS addr
//    derived per-read as (ag<<1)+kadj, kadj = par*64 - c*16 (1 VALU, CSE).
//    Halves addr regs -> __launch_bounds__(512,6): 3 blocks/CU, 24 waves.
//  * MFMA projection unchanged from R6 (A-frag = conv output directly).

#define VOCABSZ 67
#define EMBSZ   32
#define NCH     32
#define NFEAT   96
#define SEQL    16
#define BATCH   131072
#define NTAB    9
#define NENT    (NTAB * VOCABSZ)           // 603 table entries
#define TABU    (NENT * NCH / 2)           // 9648 u32 words of f16 tables
#define PWOFF   TABU                       // packed pw follows tables in ws
#define NFP     (NFEAT / 2)                // 48 feature pairs
#define NPW     (NFEAT * NFP)              // 4608 packed pw words
#define GTS     4288                       // global: 67 entries * 64 B/table
#define LTS     8576                       // LDS: 67 entries * 128 B/table
#define LDSB    (5 * LTS)                  // 42880 B: tables 0..4 replicated
#define G4BASE  (5 * GTS)                  // conv4 tables start byte in ws

typedef _Float16 v2h __attribute__((ext_vector_type(2)));
typedef _Float16 v8h __attribute__((ext_vector_type(8)));
typedef float    v4f __attribute__((ext_vector_type(4)));

__device__ __forceinline__ unsigned packh2(float a, float b) {
    v2h p; p[0] = (_Float16)a; p[1] = (_Float16)b;
    return __builtin_bit_cast(unsigned, p);
}

// ------------- kernel 1: f16 tables + packed pw into d_ws ------------------
__global__ __launch_bounds__(256) void build_tables(
    const float* __restrict__ embed,
    const float* __restrict__ w2, const float* __restrict__ b2,
    const float* __restrict__ w3, const float* __restrict__ b3,
    const float* __restrict__ w4, const float* __restrict__ b4,
    const float* __restrict__ pw,
    unsigned* __restrict__ ws)
{
    int idx = blockIdx.x * 256 + threadIdx.x;
    if (idx < TABU) {                      // one half2 (2 channels) per thread
        int cp = idx & 15;                 // channel pair 0..15
        int t  = idx >> 4;                 // j*67 + v
        int j  = t / VOCABSZ;
        int v  = t - j * VOCABSZ;
        const float* w; const float* bias; int k, h;
        if (j < 2)      { w = w2; k = 2; h = j;     bias = (h == 0) ? b2 : nullptr; }
        else if (j < 5) { w = w3; k = 3; h = j - 2; bias = (h == 0) ? b3 : nullptr; }
        else            { w = w4; k = 4; h = j - 5; bias = (h == 0) ? b4 : nullptr; }
        int c0 = 2 * cp;
        float a0 = bias ? bias[c0]     : 0.0f;
        float a1 = bias ? bias[c0 + 1] : 0.0f;
        if (v != 0) {                      // padding_idx=0: row 0 is zeros
            #pragma unroll
            for (int e = 0; e < EMBSZ; ++e) {
                float ev = embed[v * EMBSZ + e];
                a0 += ev * w[((c0    ) * EMBSZ + e) * k + h];
                a1 += ev * w[((c0 + 1) * EMBSZ + e) * k + h];
            }
        }
        ws[t * 16 + cp] = packh2(a0, a1);
    } else if (idx < TABU + NPW) {         // packed pw: pwh[o][fp]
        int i  = idx - TABU;
        int o  = i / NFP;
        int fp = i - o * NFP;
        ws[PWOFF + i] = packh2(pw[o * NFEAT + 2 * fp], pw[o * NFEAT + 2 * fp + 1]);
    }
}

// ------------- kernel 2: fused conv-as-lookup + max + MFMA projection ------
// LDS conv batch: N positions, K taps, table base byte TB (tables 0..4).
// Address = (ag[p]<<1) + kadj maps the 64B-global form to 128B-replicated
// LDS lines. All indices compile-time after unroll (rule #20).
template<int K, int N, int P0, int TB>
__device__ __forceinline__ void lconv(const char* __restrict__ base,
                                      const int (&ag)[16], int kadj, v8h& m)
{
    v8h s[N];
    #pragma unroll
    for (int u = 0; u < N; ++u)
        s[u] = *reinterpret_cast<const v8h*>(base + TB + ((ag[P0 + u] << 1) + kadj));
    #pragma unroll
    for (int h = 1; h < K; ++h) {
        v8h t[N];
        #pragma unroll
        for (int u = 0; u < N; ++u)
            t[u] = *reinterpret_cast<const v8h*>(base + TB + h * LTS + ((ag[P0 + u + h] << 1) + kadj));
        #pragma unroll
        for (int u = 0; u < N; ++u) s[u] = s[u] + t[u];
    }
    #pragma unroll
    for (int u = 0; u < N; ++u) m = __builtin_elementwise_max(m, s[u]);
}

// Global conv batch (conv4, tables 5..8 in ws, 64B entries, L1-resident).
template<int K, int N, int P0>
__device__ __forceinline__ void gconv(const char* __restrict__ g4,
                                      const int (&ag)[16], v8h& m)
{
    v8h s[N];
    #pragma unroll
    for (int u = 0; u < N; ++u)
        s[u] = *reinterpret_cast<const v8h*>(g4 + ag[P0 + u]);
    #pragma unroll
    for (int h = 1; h < K; ++h) {
        v8h t[N];
        #pragma unroll
        for (int u = 0; u < N; ++u)
            t[u] = *reinterpret_cast<const v8h*>(g4 + h * GTS + ag[P0 + u + h]);
        #pragma unroll
        for (int u = 0; u < N; ++u) s[u] = s[u] + t[u];
    }
    #pragma unroll
    for (int u = 0; u < N; ++u) m = __builtin_elementwise_max(m, s[u]);
}

__global__ __launch_bounds__(512, 6) void fused_cnn(
    const int*      __restrict__ x,
    const unsigned* __restrict__ ws,
    const float*    __restrict__ pb,
    float*          __restrict__ out)
{
    extern __shared__ __align__(16) char ldsraw[];
    const int tid = threadIdx.x;
    {   // stage tables 0..4 (335 entries x 64B) with parity replication
        const float4* s4 = reinterpret_cast<const float4*>(ws);
        float4* d4 = reinterpret_cast<float4*>(ldsraw);
        #pragma unroll
        for (int i0 = 0; i0 < 1536; i0 += 512) {
            int i = i0 + tid;
            if (i < 1340) {
                int t = i >> 2, c = i & 3;
                float4 v = s4[i];
                d4[t * 8 + c]     = v;   // parity 0
                d4[t * 8 + 4 + c] = v;   // parity 1 (+64 B)
            }
        }
    }
    __syncthreads();

    const int lane = tid & 63;
    const int wv   = tid >> 6;               // wave 0..7
    const int ml   = lane & 15;              // row within wave's 16-row tile
    const int c    = lane >> 4;              // fixed chunk = MFMA k-group
    const int par  = (lane >> 3) & 1;        // parity replica choice (LDS)
    const int kadj = (par << 6) - (c << 4);  // (ag<<1)+kadj -> LDS byte addr
    const int co   = c << 4;                 // global chunk byte offset
    const int rowb = blockIdx.x * 128 + wv * 16;
    const int row  = rowb + ml;
    const char* base = ldsraw;
    const char* g4   = reinterpret_cast<const char*>(ws) + G4BASE;

    const int4* xp = reinterpret_cast<const int4*>(x + row * SEQL);
    int4 q0 = xp[0], q1 = xp[1], q2 = xp[2], q3 = xp[3];
    int ag[16];                               // global-form addr: tok*64 + c*16
    ag[ 0] = (q0.x << 6) + co; ag[ 1] = (q0.y << 6) + co;
    ag[ 2] = (q0.z << 6) + co; ag[ 3] = (q0.w << 6) + co;
    ag[ 4] = (q1.x << 6) + co; ag[ 5] = (q1.y << 6) + co;
    ag[ 6] = (q1.z << 6) + co; ag[ 7] = (q1.w << 6) + co;
    ag[ 8] = (q2.x << 6) + co; ag[ 9] = (q2.y << 6) + co;
    ag[10] = (q2.z << 6) + co; ag[11] = (q2.w << 6) + co;
    ag[12] = (q3.x << 6) + co; ag[13] = (q3.y << 6) + co;
    ag[14] = (q3.z << 6) + co; ag[15] = (q3.w << 6) + co;

    v8h m2 = {}, m3 = {}, m4 = {};            // feats >= 0 -> 0-init max-safe

    // Interleave global (conv4: 13 pos) with LDS (conv2: 15, conv3: 14)
    // batches so both pipes fill concurrently.
    gconv<4, 3,  0>(g4, ag, m4);
    lconv<2, 4,  0, 0 * LTS>(base, ag, kadj, m2);
    gconv<4, 3,  3>(g4, ag, m4);
    lconv<2, 4,  4, 0 * LTS>(base, ag, kadj, m2);
    gconv<4, 3,  6>(g4, ag, m4);
    lconv<2, 4,  8, 0 * LTS>(base, ag, kadj, m2);
    gconv<4, 2,  9>(g4, ag, m4);
    lconv<2, 3, 12, 0 * LTS>(base, ag, kadj, m2);
    gconv<4, 2, 11>(g4, ag, m4);
    lconv<3, 4,  0, 2 * LTS>(base, ag, kadj, m3);
    lconv<3, 4,  4, 2 * LTS>(base, ag, kadj, m3);
    lconv<3, 3,  8, 2 * LTS>(base, ag, kadj, m3);
    lconv<3, 3, 11, 2 * LTS>(base, ag, kadj, m3);

    // ---- projection: O[16 rows][96] = feat x pw^T via 18 mfma 16x16x32 ----
    // A-fragment: lane holds A[ml][8c..8c+7] per k-tile = m2/m3/m4 directly.
    const unsigned* __restrict__ pwp = ws + PWOFF + ml * NFP + c * 4;
    #pragma unroll
    for (int u = 0; u < 6; ++u) {
        v4f acc = {0.f, 0.f, 0.f, 0.f};
        v8h b0 = *reinterpret_cast<const v8h*>(pwp + 768 * u);
        v8h b1 = *reinterpret_cast<const v8h*>(pwp + 768 * u + 16);
        v8h b2 = *reinterpret_cast<const v8h*>(pwp + 768 * u + 32);
        acc = __builtin_amdgcn_mfma_f32_16x16x32_f16(m2, b0, acc, 0, 0, 0);
        acc = __builtin_amdgcn_mfma_f32_16x16x32_f16(m3, b1, acc, 0, 0, 0);
        acc = __builtin_amdgcn_mfma_f32_16x16x32_f16(m4, b2, acc, 0, 0, 0);
        // D: row m = c*4 + r (local), col n = 16u + ml. Bias + ReLU at store.
        float pbl = pb[16 * u + ml];
        #pragma unroll
        for (int r = 0; r < 4; ++r)
            out[(size_t)(rowb + c * 4 + r) * NFEAT + 16 * u + ml] =
                fmaxf(acc[r] + pbl, 0.f);
    }
}

extern "C" void kernel_launch(void* const* d_in, const int* in_sizes, int n_in,
                              void* d_out, int out_size, void* d_ws, size_t ws_size,
                              hipStream_t stream)
{
    const int*   x     = (const int*)  d_in[0];
    const float* embed = (const float*)d_in[1];
    const float* w2    = (const float*)d_in[2];
    const float* b2    = (const float*)d_in[3];
    const float* w3    = (const float*)d_in[4];
    const float* b3    = (const float*)d_in[5];
    const float* w4    = (const float*)d_in[6];
    const float* b4    = (const float*)d_in[7];
    const float* pw    = (const float*)d_in[8];
    const float* pb    = (const float*)d_in[9];
    float* out = (float*)d_out;
    unsigned* ws = (unsigned*)d_ws;      // 9648 + 4608 u32 = 57 KB used

    build_tables<<<(TABU + NPW + 255) / 256, 256, 0, stream>>>(
        embed, w2, b2, w3, b3, w4, b4, pw, ws);

    // 4 threads/row, 128 rows/block -> grid 1024; 42.9KB LDS -> 3 blocks/CU
    // (24 waves) if VGPR <= ~85 (launch_bounds 512,6).
    fused_cnn<<<BATCH / 128, 512, LDSB, stream>>>(x, ws, pb, out);
}

// Round 8
// 41.002 us; speedup vs baseline: 1.5486x; 1.5486x over previous
//
#include <hip/hip_runtime.h>
#include <hip/hip_fp16.h>

// GeneSymbolCNN: embed(67x32, pad0) -> conv1d k=2/3/4 (32ch) + ReLU + max_t
//                -> concat(96) -> 96x96 linear + ReLU.
// Conv-over-embedding factors into per-token f16 tables:
//   T_{k,h}[v][c] = sum_e embed[v,e] * w_k[c,e,h]  (bias folded into h=0)
// R8 vs R7 (54.6us: global-gather path starved of ILP, VGPR squeezed to 36)
// and R6 (40us, 77KB replicated LDS, 2 blocks/CU): all-LDS again, but with
// UNREPLICATED 80B-padded entries (64B data + 16B pad):
//   span = addr/16 mod 8 = (5*tok + c) mod 8, 5 coprime 8 -> token-random
//   4-span runs per 16-lane row group (R1-measured ~6 extra cyc/instr,
//   comparable to replicated), and LDS drops 77.2 -> 48.2 KB ->
//   3 blocks/CU = 24 waves (6/SIMD), 1.5x the latency hiding of R6.
// Structure otherwise verbatim R6 (channel-split 4 thr/row, conv output =
// MFMA A-fragment, 18 mfma projection). __launch_bounds__(512,6) caps
// VGPR at 85 (needed for 6 waves/SIMD); working set ~65.

#define VOCABSZ 67
#define EMBSZ   32
#define NCH     32
#define NFEAT   96
#define SEQL    16
#define BATCH   131072
#define NTAB    9
#define NENT    (NTAB * VOCABSZ)           // 603 table entries
#define TABU    (NENT * NCH / 2)           // 9648 u32 words of f16 tables
#define PWOFF   TABU                       // packed pw follows tables in ws
#define NFP     (NFEAT / 2)                // 48 feature pairs
#define NPW     (NFEAT * NFP)              // 4608 packed pw words
#define ESTR    80                         // LDS bytes per entry (64 + 16 pad)
#define LTS     (VOCABSZ * ESTR)           // 5360 B per table in LDS
#define LDSB    (NTAB * LTS)               // 48240 B total

typedef _Float16 v2h __attribute__((ext_vector_type(2)));
typedef _Float16 v8h __attribute__((ext_vector_type(8)));
typedef float    v4f __attribute__((ext_vector_type(4)));

__device__ __forceinline__ unsigned packh2(float a, float b) {
    v2h p; p[0] = (_Float16)a; p[1] = (_Float16)b;
    return __builtin_bit_cast(unsigned, p);
}

// ------------- kernel 1: f16 tables + packed pw into d_ws ------------------
__global__ __launch_bounds__(256) void build_tables(
    const float* __restrict__ embed,
    const float* __restrict__ w2, const float* __restrict__ b2,
    const float* __restrict__ w3, const float* __restrict__ b3,
    const float* __restrict__ w4, const float* __restrict__ b4,
    const float* __restrict__ pw,
    unsigned* __restrict__ ws)
{
    int idx = blockIdx.x * 256 + threadIdx.x;
    if (idx < TABU) {                      // one half2 (2 channels) per thread
        int cp = idx & 15;                 // channel pair 0..15
        int t  = idx >> 4;                 // j*67 + v
        int j  = t / VOCABSZ;
        int v  = t - j * VOCABSZ;
        const float* w; const float* bias; int k, h;
        if (j < 2)      { w = w2; k = 2; h = j;     bias = (h == 0) ? b2 : nullptr; }
        else if (j < 5) { w = w3; k = 3; h = j - 2; bias = (h == 0) ? b3 : nullptr; }
        else            { w = w4; k = 4; h = j - 5; bias = (h == 0) ? b4 : nullptr; }
        int c0 = 2 * cp;
        float a0 = bias ? bias[c0]     : 0.0f;
        float a1 = bias ? bias[c0 + 1] : 0.0f;
        if (v != 0) {                      // padding_idx=0: row 0 is zeros
            #pragma unroll
            for (int e = 0; e < EMBSZ; ++e) {
                float ev = embed[v * EMBSZ + e];
                a0 += ev * w[((c0    ) * EMBSZ + e) * k + h];
                a1 += ev * w[((c0 + 1) * EMBSZ + e) * k + h];
            }
        }
        ws[t * 16 + cp] = packh2(a0, a1);
    } else if (idx < TABU + NPW) {         // packed pw: pwh[o][fp]
        int i  = idx - TABU;
        int o  = i / NFP;
        int fp = i - o * NFP;
        ws[PWOFF + i] = packh2(pw[o * NFEAT + 2 * fp], pw[o * NFEAT + 2 * fp + 1]);
    }
}

// ------------- kernel 2: fused conv-as-lookup + max + MFMA projection ------
// N conv positions (P0..P0+N-1) of a K-tap conv, table base byte TB.
// All indices compile-time after unroll (rule #20). N loads in flight/tap.
template<int K, int N, int P0, int TB>
__device__ __forceinline__ void lconv(const char* __restrict__ base,
                                      const int (&ap)[16], v8h& m)
{
    v8h s[N];
    #pragma unroll
    for (int u = 0; u < N; ++u)
        s[u] = *reinterpret_cast<const v8h*>(base + TB + ap[P0 + u]);
    #pragma unroll
    for (int h = 1; h < K; ++h) {
        v8h t[N];
        #pragma unroll
        for (int u = 0; u < N; ++u)
            t[u] = *reinterpret_cast<const v8h*>(base + TB + h * LTS + ap[P0 + u + h]);
        #pragma unroll
        for (int u = 0; u < N; ++u) s[u] = s[u] + t[u];
    }
    #pragma unroll
    for (int u = 0; u < N; ++u) m = __builtin_elementwise_max(m, s[u]);
}

__global__ __launch_bounds__(512, 6) void fused_cnn(
    const int*      __restrict__ x,
    const unsigned* __restrict__ ws,
    const float*    __restrict__ pb,
    float*          __restrict__ out)
{
    extern __shared__ __align__(16) char ldsraw[];
    const int tid = threadIdx.x;
    {   // stage 2412 float4 of tables into 80B-strided entries
        const float4* s4 = reinterpret_cast<const float4*>(ws);
        float4* d4 = reinterpret_cast<float4*>(ldsraw);
        #pragma unroll
        for (int i0 = 0; i0 < 2560; i0 += 512) {
            int i = i0 + tid;
            if (i < 2412) {
                int t = i >> 2, c = i & 3;
                d4[5 * t + c] = s4[i];     // byte addr t*80 + c*16
            }
        }
    }
    __syncthreads();

    const int lane = tid & 63;
    const int wv   = tid >> 6;               // wave 0..7
    const int ml   = lane & 15;              // row within wave's 16-row tile
    const int c    = lane >> 4;              // fixed chunk = MFMA k-group
    const int co   = c << 4;                 // chunk byte offset in entry
    const int rowb = blockIdx.x * 128 + wv * 16;
    const int row  = rowb + ml;
    const char* base = ldsraw;

    const int4* xp = reinterpret_cast<const int4*>(x + row * SEQL);
    int4 q0 = xp[0], q1 = xp[1], q2 = xp[2], q3 = xp[3];
    int ap[16];                               // entry byte offset + chunk
    ap[ 0] = q0.x * ESTR + co; ap[ 1] = q0.y * ESTR + co;
    ap[ 2] = q0.z * ESTR + co; ap[ 3] = q0.w * ESTR + co;
    ap[ 4] = q1.x * ESTR + co; ap[ 5] = q1.y * ESTR + co;
    ap[ 6] = q1.z * ESTR + co; ap[ 7] = q1.w * ESTR + co;
    ap[ 8] = q2.x * ESTR + co; ap[ 9] = q2.y * ESTR + co;
    ap[10] = q2.z * ESTR + co; ap[11] = q2.w * ESTR + co;
    ap[12] = q3.x * ESTR + co; ap[13] = q3.y * ESTR + co;
    ap[14] = q3.z * ESTR + co; ap[15] = q3.w * ESTR + co;

    v8h m2 = {}, m3 = {}, m4 = {};            // feats >= 0 -> 0-init max-safe

    // conv2: tables 0,1 ; positions 0..14
    lconv<2, 5,  0, 0 * LTS>(base, ap, m2);
    lconv<2, 5,  5, 0 * LTS>(base, ap, m2);
    lconv<2, 5, 10, 0 * LTS>(base, ap, m2);
    // conv3: tables 2,3,4 ; positions 0..13
    lconv<3, 5,  0, 2 * LTS>(base, ap, m3);
    lconv<3, 5,  5, 2 * LTS>(base, ap, m3);
    lconv<3, 4, 10, 2 * LTS>(base, ap, m3);
    // conv4: tables 5,6,7,8 ; positions 0..12
    lconv<4, 5,  0, 5 * LTS>(base, ap, m4);
    lconv<4, 4,  5, 5 * LTS>(base, ap, m4);
    lconv<4, 4,  9, 5 * LTS>(base, ap, m4);

    // ---- projection: O[16 rows][96] = feat x pw^T via 18 mfma 16x16x32 ----
    // A-fragment: lane holds A[ml][8c..8c+7] per k-tile = m2/m3/m4 directly.
    // B-fragment: pw[n = 16u+ml][k-tile t, 8c..8c+7] from ws (L1-resident).
    const unsigned* __restrict__ pwp = ws + PWOFF + ml * NFP + c * 4;
    #pragma unroll
    for (int u = 0; u < 6; ++u) {
        v4f acc = {0.f, 0.f, 0.f, 0.f};
        v8h b0 = *reinterpret_cast<const v8h*>(pwp + 768 * u);
        v8h b1 = *reinterpret_cast<const v8h*>(pwp + 768 * u + 16);
        v8h b2 = *reinterpret_cast<const v8h*>(pwp + 768 * u + 32);
        acc = __builtin_amdgcn_mfma_f32_16x16x32_f16(m2, b0, acc, 0, 0, 0);
        acc = __builtin_amdgcn_mfma_f32_16x16x32_f16(m3, b1, acc, 0, 0, 0);
        acc = __builtin_amdgcn_mfma_f32_16x16x32_f16(m4, b2, acc, 0, 0, 0);
        // D: row m = c*4 + r (local), col n = 16u + ml. Bias + ReLU at store.
        float pbl = pb[16 * u + ml];
        #pragma unroll
        for (int r = 0; r < 4; ++r)
            out[(size_t)(rowb + c * 4 + r) * NFEAT + 16 * u + ml] =
                fmaxf(acc[r] + pbl, 0.f);
    }
}

extern "C" void kernel_launch(void* const* d_in, const int* in_sizes, int n_in,
                              void* d_out, int out_size, void* d_ws, size_t ws_size,
                              hipStream_t stream)
{
    const int*   x     = (const int*)  d_in[0];
    const float* embed = (const float*)d_in[1];
    const float* w2    = (const float*)d_in[2];
    const float* b2    = (const float*)d_in[3];
    const float* w3    = (const float*)d_in[4];
    const float* b3    = (const float*)d_in[5];
    const float* w4    = (const float*)d_in[6];
    const float* b4    = (const float*)d_in[7];
    const float* pw    = (const float*)d_in[8];
    const float* pb    = (const float*)d_in[9];
    float* out = (float*)d_out;
    unsigned* ws = (unsigned*)d_ws;      // 9648 + 4608 u32 = 57 KB used

    build_tables<<<(TABU + NPW + 255) / 256, 256, 0, stream>>>(
        embed, w2, b2, w3, b3, w4, b4, pw, ws);

    (void)hipFuncSetAttribute((const void*)fused_cnn,
                              hipFuncAttributeMaxDynamicSharedMemorySize,
                              LDSB);
    // 4 threads/row, 128 rows/block -> grid 1024; 48.2KB LDS -> 3 blocks/CU
    // (24 waves/CU) at VGPR <= 85 (launch_bounds 512,6).
    fused_cnn<<<BATCH / 128, 512, LDSB, stream>>>(x, ws, pb, out);
}